// Round 6
// baseline (1855.049 us; speedup 1.0000x reference)
//
#include <hip/hip_runtime.h>
#include <math.h>

#define NN 100000
#define EE 640000
#define DD 128
#define NB_SCAN ((NN + 255) / 256)   // 391
#define NTILES 6250                   // NN/16 exactly
#define NBLK_R 512
#define NWAVES_R (NBLK_R * 4)

typedef __attribute__((ext_vector_type(8))) short bf16x8;
typedef __attribute__((ext_vector_type(4))) float f32x4;

static __device__ __forceinline__ float4 ld4(const float* p) {
    return *reinterpret_cast<const float4*>(p);
}

// fp32 -> bf16 RNE
static __device__ __forceinline__ unsigned short f2bf(float x) {
    unsigned u = __float_as_uint(x);
    return (unsigned short)((u + 0x7FFFu + ((u >> 16) & 1u)) >> 16);
}

// RNE split (used in one-time W pre-pack only)
static __device__ __forceinline__ void splitbf(float a, short& hi, short& lo) {
    unsigned u = __float_as_uint(a);
    unsigned hr = (u + 0x7FFFu + ((u >> 16) & 1u)) >> 16;
    float hf = __uint_as_float(hr << 16);
    float l = a - hf;
    unsigned ul = __float_as_uint(l);
    unsigned lr = (ul + 0x7FFFu + ((ul >> 16) & 1u)) >> 16;
    hi = (short)hr; lo = (short)lr;
}

// trunc split (hot path, 4 VALU): a = hi + l exactly; lo = trunc16(l); err <= 2^-18|a|
static __device__ __forceinline__ void splitbf_t(float a, short& hi, short& lo) {
    unsigned u = __float_as_uint(a);
    hi = (short)(u >> 16);
    float l = a - __uint_as_float(u & 0xFFFF0000u);
    lo = (short)(__float_as_uint(l) >> 16);
}

// ---------------------------------------------------------------------------
// W-fragment pre-pack. NEW column mapping so each output lane owns 8
// CONSECUTIVE logical columns:
//   frag[((ks*8+ct)*64+lane)*8 + r] = W[ks*32 + (lane>>4)*8 + r][(lane&15)*8 + ct]
// ---------------------------------------------------------------------------
__global__ void wfrag_k(const float* __restrict__ l1w, const float* __restrict__ l2w,
                        const float* __restrict__ mlp1w, const float* __restrict__ mlp2w,
                        const float* __restrict__ convw, const float* __restrict__ convlinw,
                        const float* __restrict__ post1w, const float* __restrict__ post2w,
                        unsigned short* __restrict__ Wh, unsigned short* __restrict__ Wl)
{
    const int b = blockIdx.x;
    const float* W; int slice; size_t fbase; int K;
    if (b < 12)      { W = l1w;      slice = b;      fbase = 0;      K = 128; }
    else if (b < 24) { W = l2w;      slice = b - 12; fbase = 49152;  K = 128; }
    else if (b < 48) { W = mlp1w;    slice = b - 24; fbase = 98304;  K = 256; }
    else if (b < 60) { W = mlp2w;    slice = b - 48; fbase = 196608; K = 128; }
    else if (b < 72) { W = convw;    slice = b - 60; fbase = 245760; K = 128; }
    else if (b < 84) { W = convlinw; slice = b - 72; fbase = 294912; K = 128; }
    else if (b < 88) { W = post1w;   slice = b - 84; fbase = 344064; K = 128; }
    else             { W = post2w;   slice = b - 88; fbase = 360448; K = 128; }
    const int kslices = K / 32;
    const int mat = slice / kslices;
    const int ks  = slice % kslices;
    const float* Wm = W + (size_t)mat * K * DD;
    const size_t outb = fbase + (size_t)mat * K * DD + (size_t)ks * 4096;
    const int t = threadIdx.x;
#pragma unroll
    for (int e = 0; e < 16; ++e) {
        const int f = t * 16 + e;
        const int r = f & 7, lane = (f >> 3) & 63, ct = f >> 9;
        const int krow = ks * 32 + (lane >> 4) * 8 + r;
        const int col  = (lane & 15) * 8 + ct;
        short hh, ll;
        splitbf(Wm[(size_t)krow * DD + col], hh, ll);
        Wh[outb + f] = (unsigned short)hh; Wl[outb + f] = (unsigned short)ll;
    }
}

// ---------------------------------------------------------------------------
// W-resident GEMM, fp32 A, K=128.  Entire W (hi+lo, 64KB) staged in LDS once;
// waves grid-stride row-tiles with ZERO barriers in the main loop.
// Per tile: mask+split cur -> prefetch next into cur -> 96 MFMA -> vec store.
// ---------------------------------------------------------------------------
__launch_bounds__(256, 2)
__global__ void gemmR_f32(const float* __restrict__ A,
                          const float* __restrict__ Amask,
                          const unsigned short* __restrict__ Wh,
                          const unsigned short* __restrict__ Wl,
                          const float* __restrict__ bias,
                          const int act, const int obf,
                          void* __restrict__ out, const int ldo, const int co)
{
    __shared__ __align__(16) unsigned short Bs[32768];   // 64 KB: hi | lo
    const int t = threadIdx.x, lane = t & 63;
#pragma unroll
    for (int i = 0; i < 8; ++i) {
        const int idx = i * 2048 + t * 8;
        *(uint4*)&Bs[idx]         = *(const uint4*)&Wh[idx];
        *(uint4*)&Bs[16384 + idx] = *(const uint4*)&Wl[idx];
    }
    __syncthreads();

    const int kg = lane >> 4, c16 = lane & 15;
    float bv[8];
    if (bias) {
        const float4 b0 = ld4(bias + c16 * 8), b1 = ld4(bias + c16 * 8 + 4);
        bv[0] = b0.x; bv[1] = b0.y; bv[2] = b0.z; bv[3] = b0.w;
        bv[4] = b1.x; bv[5] = b1.y; bv[6] = b1.z; bv[7] = b1.w;
    } else {
#pragma unroll
        for (int j = 0; j < 8; ++j) bv[j] = 0.f;
    }

    int tile = blockIdx.x * 4 + (t >> 6);
    float4 cur[8];
    if (tile < NTILES) {
        const float* ap = A + (size_t)(tile * 16 + c16) * DD + kg * 8;
#pragma unroll
        for (int ks = 0; ks < 4; ++ks) { cur[2*ks] = ld4(ap + ks*32); cur[2*ks+1] = ld4(ap + ks*32 + 4); }
    }
    while (tile < NTILES) {
        if (Amask) {
            const float* mp = Amask + (size_t)(tile * 16 + c16) * DD + kg * 8;
            float4 m[8];
#pragma unroll
            for (int ks = 0; ks < 4; ++ks) { m[2*ks] = ld4(mp + ks*32); m[2*ks+1] = ld4(mp + ks*32 + 4); }
#pragma unroll
            for (int q = 0; q < 8; ++q) {
                cur[q].x *= m[q].x; cur[q].y *= m[q].y; cur[q].z *= m[q].z; cur[q].w *= m[q].w;
            }
        }
        bf16x8 ah[4], al[4];
#pragma unroll
        for (int ks = 0; ks < 4; ++ks) {
            const float e[8] = {cur[2*ks].x, cur[2*ks].y, cur[2*ks].z, cur[2*ks].w,
                                cur[2*ks+1].x, cur[2*ks+1].y, cur[2*ks+1].z, cur[2*ks+1].w};
#pragma unroll
            for (int j = 0; j < 8; ++j) {
                short hh, ll; splitbf_t(e[j], hh, ll);
                ah[ks][j] = hh; al[ks][j] = ll;
            }
        }
        // prefetch next tile into cur (cur is dead after split)
        const int ntile = tile + NWAVES_R;
        if (ntile < NTILES) {
            const float* ap = A + (size_t)(ntile * 16 + c16) * DD + kg * 8;
#pragma unroll
            for (int ks = 0; ks < 4; ++ks) { cur[2*ks] = ld4(ap + ks*32); cur[2*ks+1] = ld4(ap + ks*32 + 4); }
        }
        f32x4 acc[8];
#pragma unroll
        for (int ct = 0; ct < 8; ++ct) acc[ct] = f32x4{0.f, 0.f, 0.f, 0.f};
#pragma unroll
        for (int ks = 0; ks < 4; ++ks) {
#pragma unroll
            for (int ct = 0; ct < 8; ++ct) {
                const int fo = ((ks * 8 + ct) * 64 + lane) * 8;
                const bf16x8 bh = *(const bf16x8*)&Bs[fo];
                const bf16x8 bl = *(const bf16x8*)&Bs[16384 + fo];
                acc[ct] = __builtin_amdgcn_mfma_f32_16x16x32_bf16(ah[ks], bh, acc[ct], 0, 0, 0);
                acc[ct] = __builtin_amdgcn_mfma_f32_16x16x32_bf16(al[ks], bh, acc[ct], 0, 0, 0);
                acc[ct] = __builtin_amdgcn_mfma_f32_16x16x32_bf16(ah[ks], bl, acc[ct], 0, 0, 0);
            }
        }
#pragma unroll
        for (int r = 0; r < 4; ++r) {
            const int row = tile * 16 + kg * 4 + r;
            float v[8];
#pragma unroll
            for (int ct = 0; ct < 8; ++ct) {
                v[ct] = acc[ct][r] + bv[ct];
                if (act == 1) v[ct] = fmaxf(v[ct], 0.f);
                else if (act == 2) v[ct] = 1.f / (1.f + __expf(-v[ct]));
            }
            if (obf) {
                uint4 pk;
                pk.x = (unsigned)f2bf(v[0]) | ((unsigned)f2bf(v[1]) << 16);
                pk.y = (unsigned)f2bf(v[2]) | ((unsigned)f2bf(v[3]) << 16);
                pk.z = (unsigned)f2bf(v[4]) | ((unsigned)f2bf(v[5]) << 16);
                pk.w = (unsigned)f2bf(v[6]) | ((unsigned)f2bf(v[7]) << 16);
                *(uint4*)((unsigned short*)out + (size_t)row * ldo + co + c16 * 8) = pk;
            } else {
                float* op = (float*)out + (size_t)row * ldo + co + c16 * 8;
                *(float4*)op       = make_float4(v[0], v[1], v[2], v[3]);
                *(float4*)(op + 4) = make_float4(v[4], v[5], v[6], v[7]);
            }
        }
        tile = ntile;
    }
}

// ---------------------------------------------------------------------------
// W-resident GEMM, bf16 A (exact, 2-term), K=128. Same structure.
// ---------------------------------------------------------------------------
__launch_bounds__(256, 2)
__global__ void gemmR_bf16(const unsigned short* __restrict__ A,
                           const unsigned short* __restrict__ Wh,
                           const unsigned short* __restrict__ Wl,
                           const float* __restrict__ bias,
                           const int act, const int obf,
                           void* __restrict__ out, const int ldo, const int co)
{
    __shared__ __align__(16) unsigned short Bs[32768];
    const int t = threadIdx.x, lane = t & 63;
#pragma unroll
    for (int i = 0; i < 8; ++i) {
        const int idx = i * 2048 + t * 8;
        *(uint4*)&Bs[idx]         = *(const uint4*)&Wh[idx];
        *(uint4*)&Bs[16384 + idx] = *(const uint4*)&Wl[idx];
    }
    __syncthreads();

    const int kg = lane >> 4, c16 = lane & 15;
    float bv[8];
    if (bias) {
        const float4 b0 = ld4(bias + c16 * 8), b1 = ld4(bias + c16 * 8 + 4);
        bv[0] = b0.x; bv[1] = b0.y; bv[2] = b0.z; bv[3] = b0.w;
        bv[4] = b1.x; bv[5] = b1.y; bv[6] = b1.z; bv[7] = b1.w;
    } else {
#pragma unroll
        for (int j = 0; j < 8; ++j) bv[j] = 0.f;
    }

    int tile = blockIdx.x * 4 + (t >> 6);
    bf16x8 cur[4];
    if (tile < NTILES) {
        const unsigned short* ap = A + (size_t)(tile * 16 + c16) * DD + kg * 8;
#pragma unroll
        for (int ks = 0; ks < 4; ++ks) cur[ks] = *(const bf16x8*)(ap + ks * 32);
    }
    while (tile < NTILES) {
        bf16x8 ah[4];
#pragma unroll
        for (int ks = 0; ks < 4; ++ks) ah[ks] = cur[ks];
        const int ntile = tile + NWAVES_R;
        if (ntile < NTILES) {
            const unsigned short* ap = A + (size_t)(ntile * 16 + c16) * DD + kg * 8;
#pragma unroll
            for (int ks = 0; ks < 4; ++ks) cur[ks] = *(const bf16x8*)(ap + ks * 32);
        }
        f32x4 acc[8];
#pragma unroll
        for (int ct = 0; ct < 8; ++ct) acc[ct] = f32x4{0.f, 0.f, 0.f, 0.f};
#pragma unroll
        for (int ks = 0; ks < 4; ++ks) {
#pragma unroll
            for (int ct = 0; ct < 8; ++ct) {
                const int fo = ((ks * 8 + ct) * 64 + lane) * 8;
                const bf16x8 bh = *(const bf16x8*)&Bs[fo];
                const bf16x8 bl = *(const bf16x8*)&Bs[16384 + fo];
                acc[ct] = __builtin_amdgcn_mfma_f32_16x16x32_bf16(ah[ks], bh, acc[ct], 0, 0, 0);
                acc[ct] = __builtin_amdgcn_mfma_f32_16x16x32_bf16(ah[ks], bl, acc[ct], 0, 0, 0);
            }
        }
#pragma unroll
        for (int r = 0; r < 4; ++r) {
            const int row = tile * 16 + kg * 4 + r;
            float v[8];
#pragma unroll
            for (int ct = 0; ct < 8; ++ct) {
                v[ct] = acc[ct][r] + bv[ct];
                if (act == 1) v[ct] = fmaxf(v[ct], 0.f);
                else if (act == 2) v[ct] = 1.f / (1.f + __expf(-v[ct]));
            }
            if (obf) {
                uint4 pk;
                pk.x = (unsigned)f2bf(v[0]) | ((unsigned)f2bf(v[1]) << 16);
                pk.y = (unsigned)f2bf(v[2]) | ((unsigned)f2bf(v[3]) << 16);
                pk.z = (unsigned)f2bf(v[4]) | ((unsigned)f2bf(v[5]) << 16);
                pk.w = (unsigned)f2bf(v[6]) | ((unsigned)f2bf(v[7]) << 16);
                *(uint4*)((unsigned short*)out + (size_t)row * ldo + co + c16 * 8) = pk;
            } else {
                float* op = (float*)out + (size_t)row * ldo + co + c16 * 8;
                *(float4*)op       = make_float4(v[0], v[1], v[2], v[3]);
                *(float4*)(op + 4) = make_float4(v[4], v[5], v[6], v[7]);
            }
        }
        tile = ntile;
    }
}

// ---------------------------------------------------------------------------
// Staged-loop GEMM for mlp1 (K=256, bf16 A, reluA). 16KB stages, new epilogue.
// ---------------------------------------------------------------------------
template<int KT, int MINW>
__launch_bounds__(256, MINW)
__global__ void gemm_bf16A(const unsigned short* __restrict__ A, const int reluA,
                           const unsigned short* __restrict__ Wh,
                           const unsigned short* __restrict__ Wl,
                           const float* __restrict__ bias, const int act, const int obf,
                           void* __restrict__ out, const int ldo, const int co)
{
    __shared__ __align__(16) unsigned short Bs[16384];
    const int t = threadIdx.x, lane = t & 63, w = t >> 6;
    const int kg = lane >> 4, c16 = lane & 15;
    const int rb = blockIdx.x * 64 + w * 16;
    int ra = rb + c16; if (ra >= NN) ra = NN - 1;

    bf16x8 ah[KT];
#pragma unroll
    for (int ks = 0; ks < KT; ++ks) {
        bf16x8 av = *(const bf16x8*)(A + (size_t)ra * (KT * 32) + ks * 32 + kg * 8);
        if (reluA) {
#pragma unroll
            for (int j = 0; j < 8; ++j) av[j] = (av[j] < 0) ? (short)0 : av[j];
        }
        ah[ks] = av;
    }
    float bv[8];
    if (bias) {
        const float4 b0 = ld4(bias + c16 * 8), b1 = ld4(bias + c16 * 8 + 4);
        bv[0] = b0.x; bv[1] = b0.y; bv[2] = b0.z; bv[3] = b0.w;
        bv[4] = b1.x; bv[5] = b1.y; bv[6] = b1.z; bv[7] = b1.w;
    } else {
#pragma unroll
        for (int j = 0; j < 8; ++j) bv[j] = 0.f;
    }

    f32x4 acc[8];
#pragma unroll
    for (int ct = 0; ct < 8; ++ct) acc[ct] = f32x4{0.f, 0.f, 0.f, 0.f};
#pragma unroll
    for (int st = 0; st < KT / 2; ++st) {
        if (st) __syncthreads();
#pragma unroll
        for (int i = 0; i < 4; ++i) {
            const int idx = i * 2048 + t * 8;
            *(uint4*)&Bs[idx]        = *(const uint4*)&Wh[(size_t)st * 8192 + idx];
            *(uint4*)&Bs[8192 + idx] = *(const uint4*)&Wl[(size_t)st * 8192 + idx];
        }
        __syncthreads();
#pragma unroll
        for (int s = 0; s < 2; ++s) {
            const int ks = st * 2 + s;
#pragma unroll
            for (int ct = 0; ct < 8; ++ct) {
                const int fo = ((s * 8 + ct) * 64 + lane) * 8;
                const bf16x8 bh = *(const bf16x8*)&Bs[fo];
                const bf16x8 bl = *(const bf16x8*)&Bs[8192 + fo];
                acc[ct] = __builtin_amdgcn_mfma_f32_16x16x32_bf16(ah[ks], bh, acc[ct], 0, 0, 0);
                acc[ct] = __builtin_amdgcn_mfma_f32_16x16x32_bf16(ah[ks], bl, acc[ct], 0, 0, 0);
            }
        }
    }
#pragma unroll
    for (int r = 0; r < 4; ++r) {
        const int row = rb + kg * 4 + r;
        if (row < NN) {
            float v[8];
#pragma unroll
            for (int ct = 0; ct < 8; ++ct) {
                v[ct] = acc[ct][r] + bv[ct];
                if (act == 1) v[ct] = fmaxf(v[ct], 0.f);
                else if (act == 2) v[ct] = 1.f / (1.f + __expf(-v[ct]));
            }
            if (obf) {
                uint4 pk;
                pk.x = (unsigned)f2bf(v[0]) | ((unsigned)f2bf(v[1]) << 16);
                pk.y = (unsigned)f2bf(v[2]) | ((unsigned)f2bf(v[3]) << 16);
                pk.z = (unsigned)f2bf(v[4]) | ((unsigned)f2bf(v[5]) << 16);
                pk.w = (unsigned)f2bf(v[6]) | ((unsigned)f2bf(v[7]) << 16);
                *(uint4*)((unsigned short*)out + (size_t)row * ldo + co + c16 * 8) = pk;
            } else {
                float* op = (float*)out + (size_t)row * ldo + co + c16 * 8;
                *(float4*)op       = make_float4(v[0], v[1], v[2], v[3]);
                *(float4*)(op + 4) = make_float4(v[4], v[5], v[6], v[7]);
            }
        }
    }
}

// ---------------------------------------------------------------------------
// SPMM over bf16 H (row = 64 uints = 128 bf16), fused epilogue.
// ---------------------------------------------------------------------------
__launch_bounds__(256)
__global__ void spmm_bf16(const unsigned int* __restrict__ H2,
                          const int* __restrict__ rp,
                          const int* __restrict__ ccol,
                          const float* __restrict__ cval,
                          const float* __restrict__ addend,
                          const float* __restrict__ pmask,
                          const int act, const int obf,
                          float* __restrict__ outf, unsigned int* __restrict__ outb,
                          const int ldo)
{
    const int w = (blockIdx.x * 256 + threadIdx.x) >> 6;
    if (w >= NN) return;
    const int lane = threadIdx.x & 63;
    const int s = rp[w], e = rp[w + 1];
    float ax = 0.f, ay = 0.f;
    int j = s;
    while (j < e) {
        int cnt = e - j; if (cnt > 8) cnt = 8;
        int cols[8]; float vals[8];
#pragma unroll
        for (int q = 0; q < 8; ++q) {
            if (q < cnt) { cols[q] = ccol[j + q]; vals[q] = cval[j + q]; }
        }
#pragma unroll
        for (int q = 0; q < 8; ++q) {
            if (q < cnt) {
                const unsigned u = H2[(size_t)cols[q] * 64 + lane];
                ax = fmaf(vals[q], __uint_as_float(u << 16), ax);
                ay = fmaf(vals[q], __uint_as_float(u & 0xFFFF0000u), ay);
            }
        }
        j += cnt;
    }
    if (addend) {
        const float2 t = *reinterpret_cast<const float2*>(addend + (size_t)w * DD + lane * 2);
        ax += t.x; ay += t.y;
    }
    if (pmask) {
        const float2 m = *reinterpret_cast<const float2*>(pmask + (size_t)w * DD + lane * 2);
        ax *= m.x; ay *= m.y;
    }
    if (act == 1) { ax = fmaxf(ax, 0.f); ay = fmaxf(ay, 0.f); }
    if (obf) {
        outb[(size_t)w * ldo + lane] = (unsigned)f2bf(ax) | ((unsigned)f2bf(ay) << 16);
    } else {
        float2 o; o.x = ax; o.y = ay;
        *reinterpret_cast<float2*>(outf + (size_t)w * ldo + lane * 2) = o;
    }
}

// ---------------------------------------------------------------------------
// CSR build kernels (unchanged)
// ---------------------------------------------------------------------------
__global__ void hist_k(const int* __restrict__ dstI, int* __restrict__ counts) {
    const int e = blockIdx.x * 256 + threadIdx.x;
    if (e < EE) atomicAdd(&counts[dstI[e]], 1);
}

__global__ void block_sums_k(const int* __restrict__ counts, int* __restrict__ bsum) {
    __shared__ int s[256];
    const int t = threadIdx.x;
    const int i = blockIdx.x * 256 + t;
    s[t] = (i < NN) ? counts[i] : 0;
    __syncthreads();
    for (int off = 128; off > 0; off >>= 1) {
        if (t < off) s[t] += s[t + off];
        __syncthreads();
    }
    if (t == 0) bsum[blockIdx.x] = s[0];
}

__global__ void scan_bsums_k(const int* __restrict__ bsum, int* __restrict__ bpre, const int nb) {
    __shared__ int s[512];
    const int t = threadIdx.x;
    s[t] = (t < nb) ? bsum[t] : 0;
    __syncthreads();
    for (int off = 1; off < 512; off <<= 1) {
        const int tmp = (t >= off) ? s[t - off] : 0;
        __syncthreads();
        s[t] += tmp;
        __syncthreads();
    }
    if (t < nb) bpre[t] = (t == 0) ? 0 : s[t - 1];
}

__global__ void scan_final_k(const int* __restrict__ counts, const int* __restrict__ bpre,
                             int* __restrict__ rowptr, int* __restrict__ nextc) {
    __shared__ int s[256];
    const int t = threadIdx.x;
    const int i = blockIdx.x * 256 + t;
    const int v = (i < NN) ? counts[i] : 0;
    s[t] = v;
    __syncthreads();
    for (int off = 1; off < 256; off <<= 1) {
        const int tmp = (t >= off) ? s[t - off] : 0;
        __syncthreads();
        s[t] += tmp;
        __syncthreads();
    }
    const int excl = s[t] - v + bpre[blockIdx.x];
    if (i < NN) { rowptr[i] = excl; nextc[i] = excl; }
    if (i == NN - 1) rowptr[NN] = EE;
}

__global__ void scatter_k(const int* __restrict__ srcI, const int* __restrict__ dstI,
                          const float* __restrict__ ea, int* __restrict__ nextc,
                          int* __restrict__ ccol, float* __restrict__ cval) {
    const int e = blockIdx.x * 256 + threadIdx.x;
    if (e >= EE) return;
    const int d = dstI[e];
    const int p = atomicAdd(&nextc[d], 1);
    ccol[p] = srcI[e];
    cval[p] = ea[e];
}

// ---------------------------------------------------------------------------
extern "C" void kernel_launch(void* const* d_in, const int* in_sizes, int n_in,
                              void* d_out, int out_size, void* d_ws, size_t ws_size,
                              hipStream_t stream)
{
    const float* x_in0      = (const float*)d_in[0];
    const float* edge_attr  = (const float*)d_in[1];
    const int*   edge_index = (const int*)d_in[2];
    const float* l1_b       = (const float*)d_in[6];
    const float* l2_b       = (const float*)d_in[8];
    const float* mlp1_b     = (const float*)d_in[10];
    const float* mlp2_b     = (const float*)d_in[12];
    const float* post1_b    = (const float*)d_in[14];
    const float* post2_b    = (const float*)d_in[16];

    const int* srcI = edge_index;
    const int* dstI = edge_index + EE;

    float* x_ws = (float*)d_out;   // x ping buffer (in-place-safe)

    float*          maskb  = (float*)d_ws;                     // [NN][DD] f32
    float*          tbuf   = maskb + (size_t)NN * DD;          // [NN][DD] f32
    unsigned short* h16    = (unsigned short*)(tbuf + (size_t)NN * DD);  // [NN][DD]
    unsigned short* cat16  = h16 + (size_t)NN * DD;            // [NN][2*DD]
    unsigned short* Wh_all = cat16 + (size_t)NN * 2 * DD;      // 376832
    unsigned short* Wl_all = Wh_all + 376832;                  // 376832
    float* cval   = (float*)(Wl_all + 376832);                 // [EE]
    int*   ccol   = (int*)(cval + EE);                         // [EE]
    int*   rowptr = ccol + EE;                                 // [NN+1]
    int*   nextc  = rowptr + (NN + 1);                         // [NN]
    int*   counts = nextc + NN;                                // [NN]
    int*   bsum   = counts + NN;                               // [512]
    int*   bpre   = bsum + 512;                                // [512]

    wfrag_k<<<92, 256, 0, stream>>>((const float*)d_in[5], (const float*)d_in[7],
                                    (const float*)d_in[9], (const float*)d_in[11],
                                    (const float*)d_in[3], (const float*)d_in[4],
                                    (const float*)d_in[13], (const float*)d_in[15],
                                    Wh_all, Wl_all);
    hipMemsetAsync(counts, 0, NN * sizeof(int), stream);
    hist_k      <<<(EE + 255) / 256, 256, 0, stream>>>(dstI, counts);
    block_sums_k<<<NB_SCAN, 256, 0, stream>>>(counts, bsum);
    scan_bsums_k<<<1, 512, 0, stream>>>(bsum, bpre, NB_SCAN);
    scan_final_k<<<NB_SCAN, 256, 0, stream>>>(counts, bpre, rowptr, nextc);
    scatter_k   <<<(EE + 255) / 256, 256, 0, stream>>>(srcI, dstI, edge_attr, nextc, ccol, cval);

    const int GG = (NN + 63) / 64;        // 1563 (staged mlp1 only)
    const int SPMM_GRID = NN * 64 / 256;  // 25000

    const size_t F_L1 = 0, F_L2 = 49152, F_M1 = 98304, F_M2 = 196608;
    const size_t F_CV = 245760, F_CL = 294912, F_P1 = 344064, F_P2 = 360448;

    for (int i = 0; i < 3; ++i) {
        const float* xc = (i == 0) ? x_in0 : x_ws;
        const float* pm = (i == 0) ? nullptr : maskb;   // previous-layer mask
        const size_t o128 = (size_t)i * 16384, o256 = (size_t)i * 32768;
        // h16 = bf16(xm @ l1 + b1)
        gemmR_f32<<<NBLK_R, 256, 0, stream>>>(xc, pm,
            Wh_all + F_L1 + o128, Wl_all + F_L1 + o128, l1_b + (size_t)i * DD,
            0, 1, h16, DD, 0);
        // cat16[:,128:] = bf16(xm @ l2 + b2)
        gemmR_f32<<<NBLK_R, 256, 0, stream>>>(xc, pm,
            Wh_all + F_L2 + o128, Wl_all + F_L2 + o128, l2_b + (size_t)i * DD,
            0, 1, cat16, 2 * DD, DD);
        // cat16[:,0:128] = bf16(agg(h))
        spmm_bf16<<<SPMM_GRID, 256, 0, stream>>>((const unsigned*)h16, rowptr, ccol, cval,
            nullptr, nullptr, 0, 1, nullptr, (unsigned*)cat16, 2 * DD / 2);
        // h16 = bf16(relu(relu(cat) @ mlp1 + b))    (h16 dead after spmm)
        gemm_bf16A<8, 4><<<GG, 256, 0, stream>>>(cat16, 1,
            Wh_all + F_M1 + o256, Wl_all + F_M1 + o256, mlp1_b + (size_t)i * DD, 1, 1, h16, DD, 0);
        // maskb = sigmoid(h16 @ mlp2 + b)  (f32)
        gemmR_bf16<<<NBLK_R, 256, 0, stream>>>(h16,
            Wh_all + F_M2 + o128, Wl_all + F_M2 + o128, mlp2_b + (size_t)i * DD,
            2, 0, maskb, DD, 0);
        // h16 = bf16((x*mask) @ conv_w)
        gemmR_f32<<<NBLK_R, 256, 0, stream>>>(xc, maskb,
            Wh_all + F_CV + o128, Wl_all + F_CV + o128, nullptr, 0, 1, h16, DD, 0);
        // tbuf = x @ conv_lin  (f32)
        gemmR_f32<<<NBLK_R, 256, 0, stream>>>(xc, nullptr,
            Wh_all + F_CL + o128, Wl_all + F_CL + o128, nullptr, 0, 0, tbuf, DD, 0);
        // x = relu((agg(h2) + t) * mask)  -> x_ws (f32)
        spmm_bf16<<<SPMM_GRID, 256, 0, stream>>>((const unsigned*)h16, rowptr, ccol, cval,
            tbuf, maskb, 1, 0, x_ws, nullptr, DD);
    }
    // h16 = bf16(relu(x @ post1 + b))
    gemmR_f32<<<NBLK_R, 256, 0, stream>>>(x_ws, nullptr,
        Wh_all + F_P1, Wl_all + F_P1, post1_b, 1, 1, h16, DD, 0);
    // out = h16 @ post2 + b  (f32 -> d_out)
    gemmR_bf16<<<NBLK_R, 256, 0, stream>>>(h16,
        Wh_all + F_P2, Wl_all + F_P2, post2_b, 0, 0, (float*)d_out, DD, 0);

    (void)in_sizes; (void)n_in; (void)out_size; (void)ws_size;
}

// Round 7
// 953.296 us; speedup vs baseline: 1.9459x; 1.9459x over previous
//
#include <hip/hip_runtime.h>
#include <math.h>

#define NN 100000
#define EE 640000
#define DD 128
#define NB_SCAN ((NN + 255) / 256)   // 391
#define GG 1563                       // ceil(NN/64)

typedef __attribute__((ext_vector_type(8))) short bf16x8;
typedef __attribute__((ext_vector_type(4))) float f32x4;
typedef unsigned short ush;
typedef unsigned int uint;

static __device__ __forceinline__ float4 ld4(const float* p) {
    return *reinterpret_cast<const float4*>(p);
}
static __device__ __forceinline__ ush f2bf(float x) {
    unsigned u = __float_as_uint(x);
    return (ush)((u + 0x7FFFu + ((u >> 16) & 1u)) >> 16);
}
static __device__ __forceinline__ float bf2f(short h) {
    return __uint_as_float(((unsigned)(ush)h) << 16);
}
// RNE split (one-time W pre-pack)
static __device__ __forceinline__ void splitbf(float a, short& hi, short& lo) {
    unsigned u = __float_as_uint(a);
    unsigned hr = (u + 0x7FFFu + ((u >> 16) & 1u)) >> 16;
    float l = a - __uint_as_float(hr << 16);
    unsigned ul = __float_as_uint(l);
    hi = (short)hr; lo = (short)((ul + 0x7FFFu + ((ul >> 16) & 1u)) >> 16);
}
// trunc split (hot path): err <= 2^-18 |a|
static __device__ __forceinline__ void splitbf_t(float a, short& hi, short& lo) {
    unsigned u = __float_as_uint(a);
    hi = (short)(u >> 16);
    float l = a - __uint_as_float(u & 0xFFFF0000u);
    lo = (short)(__float_as_uint(l) >> 16);
}

static __device__ __forceinline__ f32x4 MFMA(bf16x8 a, bf16x8 b, f32x4 c) {
    return __builtin_amdgcn_mfma_f32_16x16x32_bf16(a, b, c, 0, 0, 0);
}

// ---------------------------------------------------------------------------
// W-fragment pre-pack (r6 layout, verified):
//   frag[((ks*8+ct)*64+lane)*8 + r] = W[ks*32 + (lane>>4)*8 + r][(lane&15)*8 + ct]
// ---------------------------------------------------------------------------
__global__ void wfrag_k(const float* __restrict__ l1w, const float* __restrict__ l2w,
                        const float* __restrict__ mlp1w, const float* __restrict__ mlp2w,
                        const float* __restrict__ convw, const float* __restrict__ convlinw,
                        const float* __restrict__ post1w, const float* __restrict__ post2w,
                        ush* __restrict__ Wh, ush* __restrict__ Wl)
{
    const int b = blockIdx.x;
    const float* W; int slice; size_t fbase; int K;
    if (b < 12)      { W = l1w;      slice = b;      fbase = 0;      K = 128; }
    else if (b < 24) { W = l2w;      slice = b - 12; fbase = 49152;  K = 128; }
    else if (b < 48) { W = mlp1w;    slice = b - 24; fbase = 98304;  K = 256; }
    else if (b < 60) { W = mlp2w;    slice = b - 48; fbase = 196608; K = 128; }
    else if (b < 72) { W = convw;    slice = b - 60; fbase = 245760; K = 128; }
    else if (b < 84) { W = convlinw; slice = b - 72; fbase = 294912; K = 128; }
    else if (b < 88) { W = post1w;   slice = b - 84; fbase = 344064; K = 128; }
    else             { W = post2w;   slice = b - 88; fbase = 360448; K = 128; }
    const int kslices = K / 32;
    const int mat = slice / kslices;
    const int ks  = slice % kslices;
    const float* Wm = W + (size_t)mat * K * DD;
    const size_t outb = fbase + (size_t)mat * K * DD + (size_t)ks * 4096;
    const int t = threadIdx.x;
#pragma unroll
    for (int e = 0; e < 16; ++e) {
        const int f = t * 16 + e;
        const int r = f & 7, lane = (f >> 3) & 63, ct = f >> 9;
        const int krow = ks * 32 + (lane >> 4) * 8 + r;
        const int col  = (lane & 15) * 8 + ct;
        short hh, ll;
        splitbf(Wm[(size_t)krow * DD + col], hh, ll);
        Wh[outb + f] = (ush)hh; Wl[outb + f] = (ush)ll;
    }
}

// ---------------------------------------------------------------------------
// Shared building blocks: staged K=128 MFMA pass + vectorized epilogue
// ---------------------------------------------------------------------------
template<bool THREE>
static __device__ __forceinline__ void mfma_pass128(
    const bf16x8* xh, const bf16x8* xl,
    const ush* __restrict__ Wh, const ush* __restrict__ Wl,
    ush* Bs, const int t, const int lane, const bool first, f32x4* acc)
{
#pragma unroll
    for (int ct = 0; ct < 8; ++ct) acc[ct] = f32x4{0.f, 0.f, 0.f, 0.f};
#pragma unroll
    for (int st = 0; st < 2; ++st) {
        if (!(first && st == 0)) __syncthreads();
#pragma unroll
        for (int i = 0; i < 4; ++i) {
            const int idx = i * 2048 + t * 8;
            *(uint4*)&Bs[idx]        = *(const uint4*)&Wh[(size_t)st * 8192 + idx];
            *(uint4*)&Bs[8192 + idx] = *(const uint4*)&Wl[(size_t)st * 8192 + idx];
        }
        __syncthreads();
#pragma unroll
        for (int s = 0; s < 2; ++s) {
            const int ks = st * 2 + s;
#pragma unroll
            for (int ct = 0; ct < 8; ++ct) {
                const int fo = ((s * 8 + ct) * 64 + lane) * 8;
                const bf16x8 bh = *(const bf16x8*)&Bs[fo];
                const bf16x8 bl = *(const bf16x8*)&Bs[8192 + fo];
                acc[ct] = MFMA(xh[ks], bh, acc[ct]);
                if (THREE) acc[ct] = MFMA(xl[ks], bh, acc[ct]);
                acc[ct] = MFMA(xh[ks], bl, acc[ct]);
            }
        }
    }
}

static __device__ __forceinline__ void epi_store(
    const f32x4* acc, const float* __restrict__ bias, const int act, const int obf,
    void* __restrict__ out, const int ldo, const int co,
    const int rb, const int kg, const int c16)
{
    float bv[8];
    if (bias) {
        const float4 b0 = ld4(bias + c16 * 8), b1 = ld4(bias + c16 * 8 + 4);
        bv[0]=b0.x; bv[1]=b0.y; bv[2]=b0.z; bv[3]=b0.w;
        bv[4]=b1.x; bv[5]=b1.y; bv[6]=b1.z; bv[7]=b1.w;
    } else {
#pragma unroll
        for (int j = 0; j < 8; ++j) bv[j] = 0.f;
    }
#pragma unroll
    for (int r = 0; r < 4; ++r) {
        const int row = rb + kg * 4 + r;
        if (row < NN) {
            float v[8];
#pragma unroll
            for (int ct = 0; ct < 8; ++ct) {
                v[ct] = acc[ct][r] + bv[ct];
                if (act == 1) v[ct] = fmaxf(v[ct], 0.f);
                else if (act == 2) v[ct] = 1.f / (1.f + __expf(-v[ct]));
            }
            if (obf) {
                uint4 pk;
                pk.x = (uint)f2bf(v[0]) | ((uint)f2bf(v[1]) << 16);
                pk.y = (uint)f2bf(v[2]) | ((uint)f2bf(v[3]) << 16);
                pk.z = (uint)f2bf(v[4]) | ((uint)f2bf(v[5]) << 16);
                pk.w = (uint)f2bf(v[6]) | ((uint)f2bf(v[7]) << 16);
                *(uint4*)((ush*)out + (size_t)row * ldo + co + c16 * 8) = pk;
            } else {
                float* op = (float*)out + (size_t)row * ldo + co + c16 * 8;
                *(float4*)op       = make_float4(v[0], v[1], v[2], v[3]);
                *(float4*)(op + 4) = make_float4(v[4], v[5], v[6], v[7]);
            }
        }
    }
}

// ---------------------------------------------------------------------------
// Layer-0 dual GEMM, fp32 A (r5 structure). RAW1: pass1 uses unmasked A.
// ---------------------------------------------------------------------------
template<int RAW1, int MINW>
__launch_bounds__(256, MINW)
__global__ void gemm_f32A(const float* __restrict__ A,
                          const float* __restrict__ Amask,
                          const ush* __restrict__ Wh0, const ush* __restrict__ Wl0,
                          const float* __restrict__ bias0, const int act0, const int obf0,
                          void* __restrict__ out0, const int ldo0, const int co0,
                          const ush* __restrict__ Wh1, const ush* __restrict__ Wl1,
                          const float* __restrict__ bias1, const int act1, const int obf1,
                          void* __restrict__ out1, const int ldo1, const int co1)
{
    __shared__ __align__(16) ush Bs[16384];
    const int t = threadIdx.x, lane = t & 63, w = t >> 6;
    const int kg = lane >> 4, c16 = lane & 15;
    const int rb = blockIdx.x * 64 + w * 16;
    int ra = rb + c16; if (ra >= NN) ra = NN - 1;

    bf16x8 ah[4], al[4];
    bf16x8 uh[RAW1 ? 4 : 1], ul[RAW1 ? 4 : 1];
#pragma unroll
    for (int ks = 0; ks < 4; ++ks) {
        const float* ap = A + (size_t)ra * DD + ks * 32 + kg * 8;
        const float4 v0 = ld4(ap), v1 = ld4(ap + 4);
        float tmp[8] = {v0.x, v0.y, v0.z, v0.w, v1.x, v1.y, v1.z, v1.w};
        if (RAW1) {
#pragma unroll
            for (int j = 0; j < 8; ++j) { short hh, ll; splitbf_t(tmp[j], hh, ll); uh[ks][j] = hh; ul[ks][j] = ll; }
        }
        if (Amask) {
            const float* mp = Amask + (size_t)ra * DD + ks * 32 + kg * 8;
            const float4 m0 = ld4(mp), m1 = ld4(mp + 4);
            tmp[0]*=m0.x; tmp[1]*=m0.y; tmp[2]*=m0.z; tmp[3]*=m0.w;
            tmp[4]*=m1.x; tmp[5]*=m1.y; tmp[6]*=m1.z; tmp[7]*=m1.w;
        }
#pragma unroll
        for (int j = 0; j < 8; ++j) { short hh, ll; splitbf_t(tmp[j], hh, ll); ah[ks][j] = hh; al[ks][j] = ll; }
    }

    f32x4 acc[8];
    mfma_pass128<true>(ah, al, Wh0, Wl0, Bs, t, lane, true, acc);
    epi_store(acc, bias0, act0, obf0, out0, ldo0, co0, rb, kg, c16);
    mfma_pass128<true>(RAW1 ? uh : ah, RAW1 ? ul : al, Wh1, Wl1, Bs, t, lane, false, acc);
    epi_store(acc, bias1, act1, obf1, out1, ldo1, co1, rb, kg, c16);
}

// ---------------------------------------------------------------------------
// Dual GEMM over precomputed xm (bf16 hi/lo), no mask logic. layers 1,2 l1+l2.
// ---------------------------------------------------------------------------
__launch_bounds__(256, 4)
__global__ void gemm_xm(const ush* __restrict__ Ah, const ush* __restrict__ Al,
                        const ush* __restrict__ Wh0, const ush* __restrict__ Wl0,
                        const float* __restrict__ bias0, void* __restrict__ out0,
                        const int ldo0, const int co0,
                        const ush* __restrict__ Wh1, const ush* __restrict__ Wl1,
                        const float* __restrict__ bias1, void* __restrict__ out1,
                        const int ldo1, const int co1)
{
    __shared__ __align__(16) ush Bs[16384];
    const int t = threadIdx.x, lane = t & 63, w = t >> 6;
    const int kg = lane >> 4, c16 = lane & 15;
    const int rb = blockIdx.x * 64 + w * 16;
    int ra = rb + c16; if (ra >= NN) ra = NN - 1;

    bf16x8 amh[4], aml[4];
#pragma unroll
    for (int ks = 0; ks < 4; ++ks) {
        amh[ks] = *(const bf16x8*)(Ah + (size_t)ra * DD + ks * 32 + kg * 8);
        aml[ks] = *(const bf16x8*)(Al + (size_t)ra * DD + ks * 32 + kg * 8);
    }
    f32x4 acc[8];
    mfma_pass128<true>(amh, aml, Wh0, Wl0, Bs, t, lane, true, acc);
    epi_store(acc, bias0, 0, 1, out0, ldo0, co0, rb, kg, c16);
    mfma_pass128<true>(amh, aml, Wh1, Wl1, Bs, t, lane, false, acc);
    epi_store(acc, bias1, 0, 1, out1, ldo1, co1, rb, kg, c16);
}

// ---------------------------------------------------------------------------
// Conv dual for layers 1,2: A = x (bf16 hi/lo); pass0 masked -> h2, pass1 raw -> t
// ---------------------------------------------------------------------------
__launch_bounds__(256, 3)
__global__ void gemm_conv(const ush* __restrict__ Ah, const ush* __restrict__ Al,
                          const float* __restrict__ mask,
                          const ush* __restrict__ WhC, const ush* __restrict__ WlC,
                          void* __restrict__ outH,
                          const ush* __restrict__ WhL, const ush* __restrict__ WlL,
                          void* __restrict__ outT)
{
    __shared__ __align__(16) ush Bs[16384];
    const int t = threadIdx.x, lane = t & 63, w = t >> 6;
    const int kg = lane >> 4, c16 = lane & 15;
    const int rb = blockIdx.x * 64 + w * 16;
    int ra = rb + c16; if (ra >= NN) ra = NN - 1;

    bf16x8 uh[4], ul[4], amh[4], aml[4];
#pragma unroll
    for (int ks = 0; ks < 4; ++ks) {
        uh[ks] = *(const bf16x8*)(Ah + (size_t)ra * DD + ks * 32 + kg * 8);
        ul[ks] = *(const bf16x8*)(Al + (size_t)ra * DD + ks * 32 + kg * 8);
        const float* mp = mask + (size_t)ra * DD + ks * 32 + kg * 8;
        const float4 m0 = ld4(mp), m1 = ld4(mp + 4);
        const float mv[8] = {m0.x, m0.y, m0.z, m0.w, m1.x, m1.y, m1.z, m1.w};
#pragma unroll
        for (int j = 0; j < 8; ++j) {
            const float af = bf2f(uh[ks][j]) + bf2f(ul[ks][j]);
            short hh, ll; splitbf_t(af * mv[j], hh, ll);
            amh[ks][j] = hh; aml[ks][j] = ll;
        }
    }
    f32x4 acc[8];
    mfma_pass128<true>(amh, aml, WhC, WlC, Bs, t, lane, true, acc);
    epi_store(acc, nullptr, 0, 1, outH, DD, 0, rb, kg, c16);
    mfma_pass128<true>(uh, ul, WhL, WlL, Bs, t, lane, false, acc);
    epi_store(acc, nullptr, 0, 1, outT, DD, 0, rb, kg, c16);
}

// ---------------------------------------------------------------------------
// Fused 2-stage GEMM chain: out = act2(relu(A@W1+b1)@W2+b2), f32 out.
// In-wave LDS transpose (XOR-swizzled) turns stage-1 C-frags into stage-2
// A-frags with zero barriers. KT1 = K1/32 (8 for mlp, 4 for post).
// AHL: A is hi/lo split pair (3-term); else single bf16 (2-term).
// ---------------------------------------------------------------------------
template<int KT1, int AHL, int SIGE>
__launch_bounds__(256, 3)
__global__ void gemm_fused2(const ush* __restrict__ Aa, const ush* __restrict__ Ab,
                            const int reluA,
                            const ush* __restrict__ W1h, const ush* __restrict__ W1l,
                            const float* __restrict__ b1,
                            const ush* __restrict__ W2h, const ush* __restrict__ W2l,
                            const float* __restrict__ b2,
                            float* __restrict__ out)
{
    __shared__ __align__(16) ush Bs[16384];
    __shared__ __align__(16) ush Ts[8192];     // 4 waves x 16x128 bf16
    const int t = threadIdx.x, lane = t & 63, w = t >> 6;
    const int kg = lane >> 4, c16 = lane & 15;
    const int rb = blockIdx.x * 64 + w * 16;
    int ra = rb + c16; if (ra >= NN) ra = NN - 1;
    char* tsb = (char*)&Ts[w * 2048];

    bf16x8 a1h[KT1], a1l[AHL ? KT1 : 1];
#pragma unroll
    for (int ks = 0; ks < KT1; ++ks) {
        bf16x8 av = *(const bf16x8*)(Aa + (size_t)ra * (KT1 * 32) + ks * 32 + kg * 8);
        if (reluA) {
#pragma unroll
            for (int j = 0; j < 8; ++j) av[j] = (av[j] < 0) ? (short)0 : av[j];
        }
        a1h[ks] = av;
        if (AHL) a1l[ks] = *(const bf16x8*)(Ab + (size_t)ra * (KT1 * 32) + ks * 32 + kg * 8);
    }

    // ---- stage 1 ----
    f32x4 acc[8];
#pragma unroll
    for (int ct = 0; ct < 8; ++ct) acc[ct] = f32x4{0.f, 0.f, 0.f, 0.f};
#pragma unroll
    for (int st = 0; st < KT1 / 2; ++st) {
        if (st) __syncthreads();
#pragma unroll
        for (int i = 0; i < 4; ++i) {
            const int idx = i * 2048 + t * 8;
            *(uint4*)&Bs[idx]        = *(const uint4*)&W1h[(size_t)st * 8192 + idx];
            *(uint4*)&Bs[8192 + idx] = *(const uint4*)&W1l[(size_t)st * 8192 + idx];
        }
        __syncthreads();
#pragma unroll
        for (int s = 0; s < 2; ++s) {
            const int ks = st * 2 + s;
#pragma unroll
            for (int ct = 0; ct < 8; ++ct) {
                const int fo = ((s * 8 + ct) * 64 + lane) * 8;
                const bf16x8 bh = *(const bf16x8*)&Bs[fo];
                const bf16x8 bl = *(const bf16x8*)&Bs[8192 + fo];
                acc[ct] = MFMA(a1h[ks], bh, acc[ct]);
                if (AHL) acc[ct] = MFMA(a1l[ks], bh, acc[ct]);
                acc[ct] = MFMA(a1h[ks], bl, acc[ct]);
            }
        }
    }

    // ---- bias1 + relu + in-wave transpose via swizzled LDS ----
    {
        const float4 b0 = ld4(b1 + c16 * 8), b1v = ld4(b1 + c16 * 8 + 4);
        const float bv[8] = {b0.x, b0.y, b0.z, b0.w, b1v.x, b1v.y, b1v.z, b1v.w};
#pragma unroll
        for (int r = 0; r < 4; ++r) {
            const int row = kg * 4 + r;
            bf16x8 pk;
#pragma unroll
            for (int ct = 0; ct < 8; ++ct)
                pk[ct] = (short)f2bf(fmaxf(acc[ct][r] + bv[ct], 0.f));
            const int byte = (row * 256 + c16 * 16) ^ ((row & 7) << 4);
            *(bf16x8*)(tsb + byte) = pk;
        }
    }
    bf16x8 a2[4];
#pragma unroll
    for (int ks2 = 0; ks2 < 4; ++ks2) {
        const int byte = (c16 * 256 + ks2 * 64 + kg * 16) ^ ((c16 & 7) << 4);
        a2[ks2] = *(const bf16x8*)(tsb + byte);
    }

    // ---- stage 2 (K=128, 2-term) ----
#pragma unroll
    for (int ct = 0; ct < 8; ++ct) acc[ct] = f32x4{0.f, 0.f, 0.f, 0.f};
#pragma unroll
    for (int st = 0; st < 2; ++st) {
        __syncthreads();
#pragma unroll
        for (int i = 0; i < 4; ++i) {
            const int idx = i * 2048 + t * 8;
            *(uint4*)&Bs[idx]        = *(const uint4*)&W2h[(size_t)st * 8192 + idx];
            *(uint4*)&Bs[8192 + idx] = *(const uint4*)&W2l[(size_t)st * 8192 + idx];
        }
        __syncthreads();
#pragma unroll
        for (int s = 0; s < 2; ++s) {
            const int ks = st * 2 + s;
#pragma unroll
            for (int ct = 0; ct < 8; ++ct) {
                const int fo = ((s * 8 + ct) * 64 + lane) * 8;
                const bf16x8 bh = *(const bf16x8*)&Bs[fo];
                const bf16x8 bl = *(const bf16x8*)&Bs[8192 + fo];
                acc[ct] = MFMA(a2[ks], bh, acc[ct]);
                acc[ct] = MFMA(a2[ks], bl, acc[ct]);
            }
        }
    }
    epi_store(acc, b2, SIGE ? 2 : 0, 0, out, DD, 0, rb, kg, c16);
}

// ---------------------------------------------------------------------------
// SPMM (CSR by dst) over bf16 H. XOUT=0: bf16 out (cat). XOUT=1: fused
// x-update: fx = relu((sum + t)*m); writes xh/xl and optionally xm hi/lo.
// ---------------------------------------------------------------------------
template<int XOUT>
__launch_bounds__(256)
__global__ void spmm_b(const uint* __restrict__ H2,
                       const int* __restrict__ rp,
                       const int* __restrict__ ccol,
                       const float* __restrict__ cval,
                       const uint* __restrict__ tadd,
                       const float* __restrict__ pmask,
                       uint* __restrict__ o0, uint* __restrict__ o1,
                       uint* __restrict__ o2, uint* __restrict__ o3,
                       const int ldo, const int writeXM)
{
    const int w = (blockIdx.x * 256 + threadIdx.x) >> 6;
    if (w >= NN) return;
    const int lane = threadIdx.x & 63;
    const int s = rp[w], e = rp[w + 1];
    float ax = 0.f, ay = 0.f;
    int j = s;
    while (j < e) {
        int cnt = e - j; if (cnt > 8) cnt = 8;
        int cols[8]; float vals[8];
#pragma unroll
        for (int q = 0; q < 8; ++q)
            if (q < cnt) { cols[q] = ccol[j + q]; vals[q] = cval[j + q]; }
#pragma unroll
        for (int q = 0; q < 8; ++q) {
            if (q < cnt) {
                const uint u = H2[(size_t)cols[q] * 64 + lane];
                ax = fmaf(vals[q], __uint_as_float(u << 16), ax);
                ay = fmaf(vals[q], __uint_as_float(u & 0xFFFF0000u), ay);
            }
        }
        j += cnt;
    }
    if (XOUT == 0) {
        o0[(size_t)w * ldo + lane] = (uint)f2bf(ax) | ((uint)f2bf(ay) << 16);
    } else {
        const uint tu = tadd[(size_t)w * 64 + lane];
        ax += __uint_as_float(tu << 16);
        ay += __uint_as_float(tu & 0xFFFF0000u);
        const float2 m = *reinterpret_cast<const float2*>(pmask + (size_t)w * DD + lane * 2);
        ax = fmaxf(ax * m.x, 0.f);
        ay = fmaxf(ay * m.y, 0.f);
        short xh0, xl0, xh1, xl1;
        splitbf_t(ax, xh0, xl0); splitbf_t(ay, xh1, xl1);
        o0[(size_t)w * 64 + lane] = (uint)(ush)xh0 | ((uint)(ush)xh1 << 16);
        o1[(size_t)w * 64 + lane] = (uint)(ush)xl0 | ((uint)(ush)xl1 << 16);
        if (writeXM) {
            const float mx = ax * m.x, my = ay * m.y;
            short mh0, ml0, mh1, ml1;
            splitbf_t(mx, mh0, ml0); splitbf_t(my, mh1, ml1);
            o2[(size_t)w * 64 + lane] = (uint)(ush)mh0 | ((uint)(ush)mh1 << 16);
            o3[(size_t)w * 64 + lane] = (uint)(ush)ml0 | ((uint)(ush)ml1 << 16);
        }
    }
}

// ---------------------------------------------------------------------------
// CSR build (unchanged)
// ---------------------------------------------------------------------------
__global__ void hist_k(const int* __restrict__ dstI, int* __restrict__ counts) {
    const int e = blockIdx.x * 256 + threadIdx.x;
    if (e < EE) atomicAdd(&counts[dstI[e]], 1);
}
__global__ void block_sums_k(const int* __restrict__ counts, int* __restrict__ bsum) {
    __shared__ int s[256];
    const int t = threadIdx.x;
    const int i = blockIdx.x * 256 + t;
    s[t] = (i < NN) ? counts[i] : 0;
    __syncthreads();
    for (int off = 128; off > 0; off >>= 1) {
        if (t < off) s[t] += s[t + off];
        __syncthreads();
    }
    if (t == 0) bsum[blockIdx.x] = s[0];
}
__global__ void scan_bsums_k(const int* __restrict__ bsum, int* __restrict__ bpre, const int nb) {
    __shared__ int s[512];
    const int t = threadIdx.x;
    s[t] = (t < nb) ? bsum[t] : 0;
    __syncthreads();
    for (int off = 1; off < 512; off <<= 1) {
        const int tmp = (t >= off) ? s[t - off] : 0;
        __syncthreads();
        s[t] += tmp;
        __syncthreads();
    }
    if (t < nb) bpre[t] = (t == 0) ? 0 : s[t - 1];
}
__global__ void scan_final_k(const int* __restrict__ counts, const int* __restrict__ bpre,
                             int* __restrict__ rowptr, int* __restrict__ nextc) {
    __shared__ int s[256];
    const int t = threadIdx.x;
    const int i = blockIdx.x * 256 + t;
    const int v = (i < NN) ? counts[i] : 0;
    s[t] = v;
    __syncthreads();
    for (int off = 1; off < 256; off <<= 1) {
        const int tmp = (t >= off) ? s[t - off] : 0;
        __syncthreads();
        s[t] += tmp;
        __syncthreads();
    }
    const int excl = s[t] - v + bpre[blockIdx.x];
    if (i < NN) { rowptr[i] = excl; nextc[i] = excl; }
    if (i == NN - 1) rowptr[NN] = EE;
}
__global__ void scatter_k(const int* __restrict__ srcI, const int* __restrict__ dstI,
                          const float* __restrict__ ea, int* __restrict__ nextc,
                          int* __restrict__ ccol, float* __restrict__ cval) {
    const int e = blockIdx.x * 256 + threadIdx.x;
    if (e >= EE) return;
    const int d = dstI[e];
    const int p = atomicAdd(&nextc[d], 1);
    ccol[p] = srcI[e];
    cval[p] = ea[e];
}

// ---------------------------------------------------------------------------
extern "C" void kernel_launch(void* const* d_in, const int* in_sizes, int n_in,
                              void* d_out, int out_size, void* d_ws, size_t ws_size,
                              hipStream_t stream)
{
    const float* x_in0      = (const float*)d_in[0];
    const float* edge_attr  = (const float*)d_in[1];
    const int*   edge_index = (const int*)d_in[2];
    const float* l1_b       = (const float*)d_in[6];
    const float* l2_b       = (const float*)d_in[8];
    const float* mlp1_b     = (const float*)d_in[10];
    const float* mlp2_b     = (const float*)d_in[12];
    const float* post1_b    = (const float*)d_in[14];
    const float* post2_b    = (const float*)d_in[16];

    const int* srcI = edge_index;
    const int* dstI = edge_index + EE;

    float* maskb = (float*)d_out;            // gate mask lives in d_out until post12

    ush* xh     = (ush*)d_ws;                          // [NN][128]
    ush* xl     = xh  + (size_t)NN * DD;               // [NN][128]
    ush* xmh    = xl  + (size_t)NN * DD;               // [NN][128]
    ush* xml    = xmh + (size_t)NN * DD;               // [NN][128]
    ush* h16    = xml + (size_t)NN * DD;               // [NN][128]
    ush* cat16  = h16 + (size_t)NN * DD;               // [NN][256]
    ush* t16    = cat16;                               // overlay (cat dead when t written)
    ush* Wh_all = cat16 + (size_t)NN * 2 * DD;         // 376832
    ush* Wl_all = Wh_all + 376832;                     // 376832
    float* cval = (float*)(Wl_all + 376832);           // [EE]
    int* ccol   = (int*)(cval + EE);                   // [EE]
    int* rowptr = ccol + EE;                           // [NN+1]
    int* nextc  = rowptr + (NN + 1);                   // [NN]
    int* counts = nextc + NN;                          // [NN]
    int* bsum   = counts + NN;                         // [512]
    int* bpre   = bsum + 512;                          // [512]

    wfrag_k<<<92, 256, 0, stream>>>((const float*)d_in[5], (const float*)d_in[7],
                                    (const float*)d_in[9], (const float*)d_in[11],
                                    (const float*)d_in[3], (const float*)d_in[4],
                                    (const float*)d_in[13], (const float*)d_in[15],
                                    Wh_all, Wl_all);
    hipMemsetAsync(counts, 0, NN * sizeof(int), stream);
    hist_k      <<<(EE + 255) / 256, 256, 0, stream>>>(dstI, counts);
    block_sums_k<<<NB_SCAN, 256, 0, stream>>>(counts, bsum);
    scan_bsums_k<<<1, 512, 0, stream>>>(bsum, bpre, NB_SCAN);
    scan_final_k<<<NB_SCAN, 256, 0, stream>>>(counts, bpre, rowptr, nextc);
    scatter_k   <<<(EE + 255) / 256, 256, 0, stream>>>(srcI, dstI, edge_attr, nextc, ccol, cval);

    const int SPMM_GRID = NN * 64 / 256;  // 25000
    const size_t F_L1 = 0, F_L2 = 49152, F_M1 = 98304, F_M2 = 196608;
    const size_t F_CV = 245760, F_CL = 294912, F_P1 = 344064, F_P2 = 360448;

    for (int i = 0; i < 3; ++i) {
        const size_t o128 = (size_t)i * 16384, o256 = (size_t)i * 32768;
        // --- l1 + l2 dual ---
        if (i == 0) {
            gemm_f32A<0, 4><<<GG, 256, 0, stream>>>(x_in0, nullptr,
                Wh_all + F_L1, Wl_all + F_L1, l1_b, 0, 1, h16, DD, 0,
                Wh_all + F_L2, Wl_all + F_L2, l2_b, 0, 1, cat16, 2 * DD, DD);
        } else {
            gemm_xm<<<GG, 256, 0, stream>>>(xmh, xml,
                Wh_all + F_L1 + o128, Wl_all + F_L1 + o128, l1_b + (size_t)i * DD, h16, DD, 0,
                Wh_all + F_L2 + o128, Wl_all + F_L2 + o128, l2_b + (size_t)i * DD, cat16, 2 * DD, DD);
        }
        // --- cat[:,0:128] = agg(h) (bf16) ---
        spmm_b<0><<<SPMM_GRID, 256, 0, stream>>>((const uint*)h16, rowptr, ccol, cval,
            nullptr, nullptr, (uint*)cat16, nullptr, nullptr, nullptr, 128, 0);
        // --- mask = sigmoid(relu(relu(cat)@mlp1+b1)@mlp2+b2) (fused) ---
        gemm_fused2<8, 0, 1><<<GG, 256, 0, stream>>>(cat16, nullptr, 1,
            Wh_all + F_M1 + o256, Wl_all + F_M1 + o256, mlp1_b + (size_t)i * DD,
            Wh_all + F_M2 + o128, Wl_all + F_M2 + o128, mlp2_b + (size_t)i * DD, maskb);
        // --- conv dual: h2 = (x*m)@convw ; t = x@convlin ---
        if (i == 0) {
            gemm_f32A<1, 3><<<GG, 256, 0, stream>>>(x_in0, maskb,
                Wh_all + F_CV, Wl_all + F_CV, nullptr, 0, 1, h16, DD, 0,
                Wh_all + F_CL, Wl_all + F_CL, nullptr, 0, 1, t16, DD, 0);
        } else {
            gemm_conv<<<GG, 256, 0, stream>>>(xh, xl, maskb,
                Wh_all + F_CV + o128, Wl_all + F_CV + o128, h16,
                Wh_all + F_CL + o128, Wl_all + F_CL + o128, t16);
        }
        // --- x = relu((agg(h2)+t)*m); also emit xm = x*m for next layer ---
        spmm_b<1><<<SPMM_GRID, 256, 0, stream>>>((const uint*)h16, rowptr, ccol, cval,
            (const uint*)t16, maskb, (uint*)xh, (uint*)xl, (uint*)xmh, (uint*)xml, 64, (i < 2) ? 1 : 0);
    }
    // --- out = relu(x@post1+b)@post2+b (fused, f32 -> d_out over maskb) ---
    gemm_fused2<4, 1, 0><<<GG, 256, 0, stream>>>(xh, xl, 0,
        Wh_all + F_P1, Wl_all + F_P1, post1_b,
        Wh_all + F_P2, Wl_all + F_P2, post2_b, (float*)d_out);

    (void)in_sizes; (void)n_in; (void)out_size; (void)ws_size;
}